// Round 7
// baseline (119.352 us; speedup 1.0000x reference)
//
#include <hip/hip_runtime.h>

#define N_STFT 1025
#define N_MELS 128
#define BATCH 4
#define TIME 1024
#define MAX_ITER 20

typedef unsigned long long u64;
typedef unsigned int u32;

// Extract per-frequency sparse filterbank structure: each fb row f has at most
// 2 nonzeros at adjacent mel indices (m0, m0+1) — triangular filters.
__global__ void imel_prep(const float* __restrict__ fb, int* __restrict__ m0f,
                          float* __restrict__ w0a, float* __restrict__ w1a) {
  const int w = threadIdx.x >> 6, l = threadIdx.x & 63;
  const int f = blockIdx.x * 4 + w;
  if (f >= N_STFT) return;
  const float* row = fb + (size_t)f * N_MELS;
  const unsigned long long mlo = __ballot(row[l] != 0.0f);
  const unsigned long long mhi = __ballot(row[l + 64] != 0.0f);
  if (l == 0) {
    int m0 = mlo ? __builtin_ctzll(mlo)
                 : (mhi ? 64 + __builtin_ctzll(mhi) : 0);
    if (m0 > N_MELS - 2) m0 = N_MELS - 2;   // all-zero rows (f=0, f=1024) -> w=0
    m0f[f] = m0;
    w0a[f] = row[m0];
    w1a[f] = row[m0 + 1];
  }
}

// pack two rounded fixed-point values into one u64 (no inter-half carry:
// both halves are >=0 and stay < 2^31 during accumulation)
__device__ __forceinline__ u64 pk_rn(float x, float y) {
  return (u64)(u32)__float2int_rn(x) | ((u64)(u32)__float2int_rn(y) << 32);
}

// 512-thread blocks (8 waves) handle 4 rows as 2 PACKED row-pairs; waves 0-3
// own rows {0,1}, waves 4-7 own rows {2,3}; lane owns 4 contiguous freqs.
// Grid 1024 -> 4 blocks/CU = 32 waves/CU.
//
// Round-6 lesson: the kernel is LDS-instruction-issue bound (~172K wave-DS
// instrs/iter = ~64% of cycles). The sparse structure (rm/rw) is identical
// across rows, so pack 2 rows per 64-bit LDS word: ds_add_u64 scatter,
// ds_read2_b64 gather, b64 diff phase -> per-row DS instruction count halves
// while rm/rw/addresses stay shared (live set ~55 regs, under the 64 cap).
__global__ __launch_bounds__(512, 8) void imel_main(
    const float* __restrict__ melspec, const float* __restrict__ spec_init,
    const int* __restrict__ m0f, const float* __restrict__ w0a,
    const float* __restrict__ w1a, float* __restrict__ out) {
  __shared__ u64   s_PD[2][N_MELS][2];  // [pair][mel][0]=P fixed-point i32x2
                                        // [pair][mel][1]=diff' f32x2 (bits)
  __shared__ float s_out[4][1060];      // swizzle-padded: idx = f + (f>>5)

  const int tid = threadIdx.x;
  const int w   = tid >> 6;        // wave 0..7
  const int l   = tid & 63;
  const int pr  = w >> 2;          // row pair 0..1 (rows 2pr, 2pr+1)
  const int q   = w & 3;           // quarter of the freq axis
  const int c   = q * 64 + l;      // chunk 0..255 (4 freqs each)
  const int blk = blockIdx.x;
  const int b   = blk >> 8;
  const int t0  = (blk & 255) << 2;

  const float SCALE = 16777216.0f;            // 2^24 fixed point
  const float INV_SCALE = 1.0f / 16777216.0f;

  // per-lane static structure (shared across the row pair), f = 4c + k
  float rsA[4], rsB[4], rbA[4], rbB[4], rw0[4], rw1[4];
  int rm[4];

  const float* srowA = spec_init + (size_t)(b * TIME + t0 + 2 * pr) * N_STFT;
  const float* srowB = srowA + N_STFT;
#pragma unroll
  for (int k = 0; k < 4; ++k) {
    const int f = (c << 2) + k;
    rsA[k] = srowA[f];
    rsB[k] = srowB[f];
    rm[k]  = m0f[f];
    rw0[k] = w0a[f] * SCALE;
    rw1[k] = w1a[f] * SCALE;
    rbA[k] = 0.f;
    rbB[k] = 0.f;
  }
  const bool tail = (c == 255);
  const float rtA = tail ? srowA[1024] : 0.f;  // f=1024: zero fb row -> copy
  const float rtB = tail ? srowB[1024] : 0.f;

  // loop-invariant advance flags (wave masks in SGPR pairs)
  const bool adv1 = (rm[1] != rm[0]);
  const bool adv2 = (rm[2] != rm[1]);
  const bool adv3 = (rm[3] != rm[2]);

  // diff-phase role: threads 0..255 -> (pair dp, mel dm), b64 per slot
  const int dp = (tid >> 7) & 1, dm = tid & 127;
  const bool dact = tid < 256;
  // fold grad prefactor into stored diff: d' = GRAD_C*mel - GRAD_C*INV_SCALE*P
  const float GRAD_C = (-2.0f / (BATCH * TIME)) * INV_SCALE;
  const float NC2 = -GRAD_C * INV_SCALE;
  float melGlo = 0.f, melGhi = 0.f;
  if (dact) {
    const float* mp = melspec + ((size_t)b * N_MELS + dm) * TIME + t0 + 2 * dp;
    melGlo = GRAD_C * mp[0];
    melGhi = GRAD_C * mp[1];
  }

  if (dact) s_PD[dp][dm][0] = 0ULL;
  __syncthreads();

  for (int it = 0; it < MAX_ITER; ++it) {
    // ---- forward: run-compacted packed scatter (ds_add_u64) ----
    {
      float a0A = rsA[0] * rw0[0], a1A = rsA[0] * rw1[0];
      float a0B = rsB[0] * rw0[0], a1B = rsB[0] * rw1[0];
      if (adv1) atomicAdd(&s_PD[pr][rm[0]][0], pk_rn(a0A, a0B));
      a0A = (adv1 ? a1A : a0A) + rsA[1] * rw0[1];
      a1A = (adv1 ? 0.f : a1A) + rsA[1] * rw1[1];
      a0B = (adv1 ? a1B : a0B) + rsB[1] * rw0[1];
      a1B = (adv1 ? 0.f : a1B) + rsB[1] * rw1[1];
      if (adv2) atomicAdd(&s_PD[pr][rm[1]][0], pk_rn(a0A, a0B));
      a0A = (adv2 ? a1A : a0A) + rsA[2] * rw0[2];
      a1A = (adv2 ? 0.f : a1A) + rsA[2] * rw1[2];
      a0B = (adv2 ? a1B : a0B) + rsB[2] * rw0[2];
      a1B = (adv2 ? 0.f : a1B) + rsB[2] * rw1[2];
      if (adv3) atomicAdd(&s_PD[pr][rm[2]][0], pk_rn(a0A, a0B));
      a0A = (adv3 ? a1A : a0A) + rsA[3] * rw0[3];
      a1A = (adv3 ? 0.f : a1A) + rsA[3] * rw1[3];
      a0B = (adv3 ? a1B : a0B) + rsB[3] * rw0[3];
      a1B = (adv3 ? 0.f : a1B) + rsB[3] * rw1[3];
      atomicAdd(&s_PD[pr][rm[3]][0],     pk_rn(a0A, a0B));
      atomicAdd(&s_PD[pr][rm[3] + 1][0], pk_rn(a1A, a1B));
    }
    __syncthreads();
    // ---- diff' = GRAD_C*(mel - P) for both rows; reset P (all b64) ----
    if (dact) {
      const u64 p = s_PD[dp][dm][0];
      const float plo = (float)(int)(u32)p;
      const float phi = (float)(int)(u32)(p >> 32);
      const float dlo = fmaf(plo, NC2, melGlo);
      const float dhi = fmaf(phi, NC2, melGhi);
      s_PD[dp][dm][1] = (u64)__float_as_uint(dlo) |
                        ((u64)__float_as_uint(dhi) << 32);
      s_PD[dp][dm][0] = 0ULL;
    }
    __syncthreads();
    // ---- backward: ds_read2_b64 gather (2 rows/instr) + momentum + clamp ----
#pragma unroll
    for (int k = 0; k < 4; ++k) {
      const u64 wd0 = s_PD[pr][rm[k]][1];      // merges to ds_read2_b64
      const u64 wd1 = s_PD[pr][rm[k] + 1][1];
      const float d0A = __uint_as_float((u32)wd0);
      const float d0B = __uint_as_float((u32)(wd0 >> 32));
      const float d1A = __uint_as_float((u32)wd1);
      const float d1B = __uint_as_float((u32)(wd1 >> 32));
      const float gA = fmaf(d1A, rw1[k], d0A * rw0[k]);   // includes GRAD_C
      const float gB = fmaf(d1B, rw1[k], d0B * rw0[k]);
      rbA[k] = fmaf(0.9f, rbA[k], gA);
      rbB[k] = fmaf(0.9f, rbB[k], gB);
      rsA[k] = fmaxf(fmaf(-0.3f, rbA[k], rsA[k]), 0.f);
      rsB[k] = fmaxf(fmaf(-0.3f, rbB[k], rsB[k]), 0.f);
    }
    // 2 barriers/iter: backward(i) reads diff before scatter(i+1)'s barrier,
    // which gates diff(i+1)'s rewrite; P zeroed in diff phase before next add
  }

  // ---- epilogue: transpose (f-major regs) -> (B, F, T) via swizzled LDS ----
#pragma unroll
  for (int k = 0; k < 4; ++k) {
    const int f = (c << 2) + k;
    s_out[2 * pr][f + (f >> 5)]     = rsA[k];
    s_out[2 * pr + 1][f + (f >> 5)] = rsB[k];
  }
  if (tail) {
    s_out[2 * pr][1056]     = rtA;   // f=1024 -> 1024 + (1024>>5)
    s_out[2 * pr + 1][1056] = rtB;
  }
  __syncthreads();

  const int tl = tid & 3;    // t offset within the block's 4 rows
  const int fg = tid >> 2;   // 128 f phases
  float* obase = out + (size_t)b * N_STFT * TIME + t0 + tl;
  for (int f = fg; f < N_STFT; f += 128) {
    obase[(size_t)f * TIME] = s_out[tl][f + (f >> 5)];
  }
}

extern "C" void kernel_launch(void* const* d_in, const int* in_sizes, int n_in,
                              void* d_out, int out_size, void* d_ws, size_t ws_size,
                              hipStream_t stream) {
  const float* melspec = (const float*)d_in[0];
  const float* spec_init = (const float*)d_in[1];
  const float* fb = (const float*)d_in[2];
  float* out = (float*)d_out;

  int* m0f = (int*)d_ws;                          // 1025 ints
  float* w0a = (float*)((char*)d_ws + 5120);      // 1025 floats
  float* w1a = (float*)((char*)d_ws + 10240);     // 1025 floats

  imel_prep<<<dim3(257), dim3(256), 0, stream>>>(fb, m0f, w0a, w1a);
  imel_main<<<dim3(1024), dim3(512), 0, stream>>>(melspec, spec_init, m0f, w0a, w1a, out);
}